// Round 11
// baseline (1882.937 us; speedup 1.0000x reference)
//
#include <hip/hip_runtime.h>
#include <hip/hip_fp16.h>

// Problem dims
constexpr int kT = 512, kB = 32, kD = 512, kH = 256, kA1 = 16, kA2 = 128;

typedef _Float16 h2_t __attribute__((ext_vector_type(2)));
typedef _Float16 h8_t __attribute__((ext_vector_type(8)));
typedef unsigned u4_t __attribute__((ext_vector_type(4)));

#if defined(__has_builtin)
#if __has_builtin(__builtin_amdgcn_fdot2)
#define HAVE_FDOT2 1
#endif
#endif

__device__ __forceinline__ float fast_tanh(float x) {
    float e = __expf(2.0f * x);
    return 1.0f - 2.0f / (e + 1.0f);
}
__device__ __forceinline__ float fast_sig(float x) {
    return 1.0f / (1.0f + __expf(-x));
}

__device__ __forceinline__ float dot_pair(h2_t w, h2_t h, float acc) {
#if defined(HAVE_FDOT2)
    return __builtin_amdgcn_fdot2(w, h, acc, false);
#else
    acc = fmaf((float)w[0], (float)h[0], acc);
    return fmaf((float)w[1], (float)h[1], acc);
#endif
}

// ---------------- Kernel 1: attention over feature axis D -> seq (T,B) -------
__global__ __launch_bounds__(256) void att1_kernel(
    const float* __restrict__ x, const float* __restrict__ W1,
    const float* __restrict__ b1, const float* __restrict__ u1,
    float* __restrict__ seq) {
    int blk = blockIdx.x;
    int tid = threadIdx.x;
    const float* xp = x + (size_t)blk * kD;
    float x0 = xp[tid], x1 = xp[tid + 256];
    float s0 = 0.f, s1 = 0.f;
#pragma unroll
    for (int a = 0; a < kA1; ++a) {
        float w = W1[a], bb = b1[a], uu = u1[a];
        s0 += fast_tanh(fmaf(x0, w, bb)) * uu;
        s1 += fast_tanh(fmaf(x1, w, bb)) * uu;
    }
    float e0 = __expf(s0), e1 = __expf(s1);
    float se = e0 + e1;
    float sxe = fmaf(x0, e0, x1 * e1);
#pragma unroll
    for (int m = 32; m; m >>= 1) {
        se  += __shfl_xor(se,  m, 64);
        sxe += __shfl_xor(sxe, m, 64);
    }
    __shared__ float r_se[4], r_sxe[4];
    int wave = tid >> 6, lane = tid & 63;
    if (lane == 0) { r_se[wave] = se; r_sxe[wave] = sxe; }
    __syncthreads();
    if (tid == 0) {
        float S = r_se[0] + r_se[1] + r_se[2] + r_se[3];
        float X = r_sxe[0] + r_sxe[1] + r_sxe[2] + r_sxe[3];
        seq[blk] = X / S;
    }
}

// ------------- Kernel 1b: convert W_hh (4H,H) fp32 -> packed fp16 ------------
// As 16B vectors: W4[kk4*1024 + row] holds 8 consecutive k for gate row `row`.
__global__ __launch_bounds__(256) void wconv_kernel(
    const float* __restrict__ Whh, _Float16* __restrict__ WQ) {
    int idx = blockIdx.x * 256 + threadIdx.x;
    int j = idx >> 7, kk = idx & 127;
    int kk4 = kk >> 2, q = kk & 3;
    float a = Whh[j * kH + 2 * kk];
    float b = Whh[j * kH + 2 * kk + 1];
    _Float16* dst = WQ + ((size_t)kk4 * 8192 + j * 8 + q * 2);
    dst[0] = (_Float16)a;
    dst[1] = (_Float16)b;
}

// ---------------- Kernel 2: persistent per-batch LSTM ------------------------
// 256 threads (4 waves, 1/SIMD, reg cap 512). Thread j owns ALL FOUR gate
// rows of h-unit j: rows j(i), j+256(f), j+512(g), j+768(o) -> no gate
// exchange; c,h update thread-local.
//
// Residency (r10 post-mortem): any slab the register ALLOCATOR manages gets
// remat'd (r2,r7) or scratch-spilled (r5,r9,r10 — volatile "=a" results
// spilled; VGPR_Count=116 proved no AGPR allocation). Fix: HARD-NAMED
// physical AGPRs a0..a255, touched only inside asm — the allocator never
// sees them as values, so it cannot spill them. Arch pressure ~100 -> no
// compiler spills -> nothing else writes AGPRs -> slab persists.
//   pairs  0..63  of 4 rows -> a0..a255 (row r pair k -> a[r*64+k])
//   pairs 64..99  -> 144 KB LDS slab (9 slices)
//   pairs 100..127-> streamed from L2 (112 KB/step, hidden under compute)
#define LSTM_BARRIER() asm volatile("s_waitcnt lgkmcnt(0)\n\ts_barrier" ::: "memory")

#define AW(N, V) asm volatile("v_accvgpr_write_b32 a" #N ", %0" :: "v"(V) : "a" #N)
#define ARD(N, D) asm volatile("v_accvgpr_read_b32 %0, a" #N : "=v"(D))
#define AW4(N0, N1, N2, N3, Q) do { u4_t _q = (Q); \
    AW(N0, _q[0]); AW(N1, _q[1]); AW(N2, _q[2]); AW(N3, _q[3]); } while (0)

// h-pair broadcasts (lane-uniform selectors)
#define H0(KK) __builtin_bit_cast(h2_t, (unsigned)__builtin_amdgcn_readlane((int)hr0, (KK)))
#define HT(KK) __builtin_bit_cast(h2_t, (unsigned)__builtin_amdgcn_readlane((int)hr1, (KK) - 64))

// AGPR step: pair KK (<64) of all 4 rows
#define STEP(A0, A1, A2, A3, KK) do { \
    unsigned _t0, _t1, _t2, _t3; \
    ARD(A0, _t0); ARD(A1, _t1); ARD(A2, _t2); ARD(A3, _t3); \
    h2_t _hp = H0(KK); \
    acc0 = dot_pair(__builtin_bit_cast(h2_t, _t0), _hp, acc0); \
    acc1 = dot_pair(__builtin_bit_cast(h2_t, _t1), _hp, acc1); \
    acc2 = dot_pair(__builtin_bit_cast(h2_t, _t2), _hp, acc2); \
    acc3 = dot_pair(__builtin_bit_cast(h2_t, _t3), _hp, acc3); \
} while (0)

// quad step for LDS/streamed weights: 4 pairs (KKB>=64) of all 4 rows
#define DOT4Q(W0, W1, W2, W3, KKB) do { \
    h2_t _p0 = HT((KKB) + 0); \
    acc0 = dot_pair(__builtin_shufflevector((W0), (W0), 0, 1), _p0, acc0); \
    acc1 = dot_pair(__builtin_shufflevector((W1), (W1), 0, 1), _p0, acc1); \
    acc2 = dot_pair(__builtin_shufflevector((W2), (W2), 0, 1), _p0, acc2); \
    acc3 = dot_pair(__builtin_shufflevector((W3), (W3), 0, 1), _p0, acc3); \
    h2_t _p1 = HT((KKB) + 1); \
    acc0 = dot_pair(__builtin_shufflevector((W0), (W0), 2, 3), _p1, acc0); \
    acc1 = dot_pair(__builtin_shufflevector((W1), (W1), 2, 3), _p1, acc1); \
    acc2 = dot_pair(__builtin_shufflevector((W2), (W2), 2, 3), _p1, acc2); \
    acc3 = dot_pair(__builtin_shufflevector((W3), (W3), 2, 3), _p1, acc3); \
    h2_t _p2 = HT((KKB) + 2); \
    acc0 = dot_pair(__builtin_shufflevector((W0), (W0), 4, 5), _p2, acc0); \
    acc1 = dot_pair(__builtin_shufflevector((W1), (W1), 4, 5), _p2, acc1); \
    acc2 = dot_pair(__builtin_shufflevector((W2), (W2), 4, 5), _p2, acc2); \
    acc3 = dot_pair(__builtin_shufflevector((W3), (W3), 4, 5), _p2, acc3); \
    h2_t _p3 = HT((KKB) + 3); \
    acc0 = dot_pair(__builtin_shufflevector((W0), (W0), 6, 7), _p3, acc0); \
    acc1 = dot_pair(__builtin_shufflevector((W1), (W1), 6, 7), _p3, acc1); \
    acc2 = dot_pair(__builtin_shufflevector((W2), (W2), 6, 7), _p3, acc2); \
    acc3 = dot_pair(__builtin_shufflevector((W3), (W3), 6, 7), _p3, acc3); \
} while (0)

__global__ __launch_bounds__(256, 1) void lstm_kernel(
    const float* __restrict__ seq, const _Float16* __restrict__ WQ,
    const float* __restrict__ W_ih, const float* __restrict__ b_ih,
    const float* __restrict__ b_hh, const float* __restrict__ h0,
    const float* __restrict__ c0, float* __restrict__ hs) {
    int b = blockIdx.x;
    int j = threadIdx.x;          // 0..255 = h-unit
    int lane = j & 63;
    int r0 = j, r1 = j + 256, r2 = j + 512, r3 = j + 768;

    __shared__ float seq_l[kT];                           // 2 KB
    __shared__ __align__(16) u4_t wtail[9 * 1024];        // 144 KB: kk4=16..24
    __shared__ __align__(8) _Float16 hl[kH];              // 512 B

    const u4_t* W4 = (const u4_t*)WQ;

    // ---- hard-AGPR slab: pairs 0..63 (quads 0..15) of rows r0..r3 ----
    AW4(0,1,2,3,     W4[ 0*1024+r0]); AW4(4,5,6,7,     W4[ 1*1024+r0]);
    AW4(8,9,10,11,   W4[ 2*1024+r0]); AW4(12,13,14,15, W4[ 3*1024+r0]);
    AW4(16,17,18,19, W4[ 4*1024+r0]); AW4(20,21,22,23, W4[ 5*1024+r0]);
    AW4(24,25,26,27, W4[ 6*1024+r0]); AW4(28,29,30,31, W4[ 7*1024+r0]);
    AW4(32,33,34,35, W4[ 8*1024+r0]); AW4(36,37,38,39, W4[ 9*1024+r0]);
    AW4(40,41,42,43, W4[10*1024+r0]); AW4(44,45,46,47, W4[11*1024+r0]);
    AW4(48,49,50,51, W4[12*1024+r0]); AW4(52,53,54,55, W4[13*1024+r0]);
    AW4(56,57,58,59, W4[14*1024+r0]); AW4(60,61,62,63, W4[15*1024+r0]);

    AW4(64,65,66,67,     W4[ 0*1024+r1]); AW4(68,69,70,71,     W4[ 1*1024+r1]);
    AW4(72,73,74,75,     W4[ 2*1024+r1]); AW4(76,77,78,79,     W4[ 3*1024+r1]);
    AW4(80,81,82,83,     W4[ 4*1024+r1]); AW4(84,85,86,87,     W4[ 5*1024+r1]);
    AW4(88,89,90,91,     W4[ 6*1024+r1]); AW4(92,93,94,95,     W4[ 7*1024+r1]);
    AW4(96,97,98,99,     W4[ 8*1024+r1]); AW4(100,101,102,103, W4[ 9*1024+r1]);
    AW4(104,105,106,107, W4[10*1024+r1]); AW4(108,109,110,111, W4[11*1024+r1]);
    AW4(112,113,114,115, W4[12*1024+r1]); AW4(116,117,118,119, W4[13*1024+r1]);
    AW4(120,121,122,123, W4[14*1024+r1]); AW4(124,125,126,127, W4[15*1024+r1]);

    AW4(128,129,130,131, W4[ 0*1024+r2]); AW4(132,133,134,135, W4[ 1*1024+r2]);
    AW4(136,137,138,139, W4[ 2*1024+r2]); AW4(140,141,142,143, W4[ 3*1024+r2]);
    AW4(144,145,146,147, W4[ 4*1024+r2]); AW4(148,149,150,151, W4[ 5*1024+r2]);
    AW4(152,153,154,155, W4[ 6*1024+r2]); AW4(156,157,158,159, W4[ 7*1024+r2]);
    AW4(160,161,162,163, W4[ 8*1024+r2]); AW4(164,165,166,167, W4[ 9*1024+r2]);
    AW4(168,169,170,171, W4[10*1024+r2]); AW4(172,173,174,175, W4[11*1024+r2]);
    AW4(176,177,178,179, W4[12*1024+r2]); AW4(180,181,182,183, W4[13*1024+r2]);
    AW4(184,185,186,187, W4[14*1024+r2]); AW4(188,189,190,191, W4[15*1024+r2]);

    AW4(192,193,194,195, W4[ 0*1024+r3]); AW4(196,197,198,199, W4[ 1*1024+r3]);
    AW4(200,201,202,203, W4[ 2*1024+r3]); AW4(204,205,206,207, W4[ 3*1024+r3]);
    AW4(208,209,210,211, W4[ 4*1024+r3]); AW4(212,213,214,215, W4[ 5*1024+r3]);
    AW4(216,217,218,219, W4[ 6*1024+r3]); AW4(220,221,222,223, W4[ 7*1024+r3]);
    AW4(224,225,226,227, W4[ 8*1024+r3]); AW4(228,229,230,231, W4[ 9*1024+r3]);
    AW4(232,233,234,235, W4[10*1024+r3]); AW4(236,237,238,239, W4[11*1024+r3]);
    AW4(240,241,242,243, W4[12*1024+r3]); AW4(244,245,246,247, W4[13*1024+r3]);
    AW4(248,249,250,251, W4[14*1024+r3]); AW4(252,253,254,255, W4[15*1024+r3]);

    for (int t = j; t < kT; t += 256) seq_l[t] = seq[t * kB + b];

    // stage LDS slab: slices kk4 = 16..24, all 1024 rows
    for (int idx = j; idx < 9 * 1024; idx += 256)
        wtail[idx] = W4[(16 + (idx >> 10)) * 1024 + (idx & 1023)];

    float wih0 = W_ih[r0], wih1 = W_ih[r1], wih2 = W_ih[r2], wih3 = W_ih[r3];
    float bias0 = b_ih[r0] + b_hh[r0];
    float bias1 = b_ih[r1] + b_hh[r1];
    float bias2 = b_ih[r2] + b_hh[r2];
    float bias3 = b_ih[r3] + b_hh[r3];
    float c = c0[b * kH + j];
    hl[j] = (_Float16)h0[b * kH + j];
    LSTM_BARRIER();

    const unsigned* hl32 = (const unsigned*)hl;   // 128 packed fp16-pairs
    unsigned hr0 = hl32[lane];                    // pairs 0..63
    unsigned hr1 = hl32[lane + 64];               // pairs 64..127

#pragma unroll 1
    for (int t = 0; t < kT; ++t) {
        float st = seq_l[t];
        float acc0 = fmaf(st, wih0, bias0);
        float acc1 = fmaf(st, wih1, bias1);
        float acc2 = fmaf(st, wih2, bias2);
        float acc3 = fmaf(st, wih3, bias3);

        // pairs 0..63 from the hard-AGPR slab
        STEP(0,64,128,192, 0);   STEP(1,65,129,193, 1);   STEP(2,66,130,194, 2);   STEP(3,67,131,195, 3);
        STEP(4,68,132,196, 4);   STEP(5,69,133,197, 5);   STEP(6,70,134,198, 6);   STEP(7,71,135,199, 7);
        STEP(8,72,136,200, 8);   STEP(9,73,137,201, 9);   STEP(10,74,138,202, 10); STEP(11,75,139,203, 11);
        STEP(12,76,140,204, 12); STEP(13,77,141,205, 13); STEP(14,78,142,206, 14); STEP(15,79,143,207, 15);
        STEP(16,80,144,208, 16); STEP(17,81,145,209, 17); STEP(18,82,146,210, 18); STEP(19,83,147,211, 19);
        STEP(20,84,148,212, 20); STEP(21,85,149,213, 21); STEP(22,86,150,214, 22); STEP(23,87,151,215, 23);
        STEP(24,88,152,216, 24); STEP(25,89,153,217, 25); STEP(26,90,154,218, 26); STEP(27,91,155,219, 27);
        STEP(28,92,156,220, 28); STEP(29,93,157,221, 29); STEP(30,94,158,222, 30); STEP(31,95,159,223, 31);
        STEP(32,96,160,224, 32); STEP(33,97,161,225, 33); STEP(34,98,162,226, 34); STEP(35,99,163,227, 35);
        STEP(36,100,164,228, 36); STEP(37,101,165,229, 37); STEP(38,102,166,230, 38); STEP(39,103,167,231, 39);
        STEP(40,104,168,232, 40); STEP(41,105,169,233, 41); STEP(42,106,170,234, 42); STEP(43,107,171,235, 43);
        STEP(44,108,172,236, 44); STEP(45,109,173,237, 45); STEP(46,110,174,238, 46); STEP(47,111,175,239, 47);
        STEP(48,112,176,240, 48); STEP(49,113,177,241, 49); STEP(50,114,178,242, 50); STEP(51,115,179,243, 51);
        STEP(52,116,180,244, 52); STEP(53,117,181,245, 53); STEP(54,118,182,246, 54); STEP(55,119,183,247, 55);
        STEP(56,120,184,248, 56); STEP(57,121,185,249, 57); STEP(58,122,186,250, 58); STEP(59,123,187,251, 59);
        STEP(60,124,188,252, 60); STEP(61,125,189,253, 61); STEP(62,126,190,254, 62); STEP(63,127,191,255, 63);

        // pairs 64..99 from the LDS slab (9 slices)
#pragma unroll 3
        for (int q = 0; q < 9; ++q) {
            h8_t w0 = __builtin_bit_cast(h8_t, wtail[q * 1024 + r0]);
            h8_t w1 = __builtin_bit_cast(h8_t, wtail[q * 1024 + r1]);
            h8_t w2 = __builtin_bit_cast(h8_t, wtail[q * 1024 + r2]);
            h8_t w3 = __builtin_bit_cast(h8_t, wtail[q * 1024 + r3]);
            DOT4Q(w0, w1, w2, w3, 64 + q * 4);
        }
        // pairs 100..127 streamed from L2 (7 slices; latency hidden by compute)
#pragma unroll 7
        for (int q = 0; q < 7; ++q) {
            h8_t w0 = __builtin_bit_cast(h8_t, W4[(25 + q) * 1024 + r0]);
            h8_t w1 = __builtin_bit_cast(h8_t, W4[(25 + q) * 1024 + r1]);
            h8_t w2 = __builtin_bit_cast(h8_t, W4[(25 + q) * 1024 + r2]);
            h8_t w3 = __builtin_bit_cast(h8_t, W4[(25 + q) * 1024 + r3]);
            DOT4Q(w0, w1, w2, w3, 100 + q * 4);
        }

        // thread-local gate combine: acc0=i, acc1=f, acc2=g, acc3=o
        float ig = fast_sig(acc0);
        float fg = fast_sig(acc1);
        float gg = fast_tanh(acc2);
        float og = fast_sig(acc3);
        c = fmaf(fg, c, ig * gg);
        float h = og * fast_tanh(c);
        hs[(size_t)t * (kB * kH) + b * kH + j] = h;   // store floats, never drained
        hl[j] = (_Float16)h;
        LSTM_BARRIER();
        hr0 = hl32[lane];
        hr1 = hl32[lane + 64];
        LSTM_BARRIER();
    }
}

// ---------------- Kernel 3a: attention-2 scores e2 (T,B) ---------------------
__global__ __launch_bounds__(128) void att2a_kernel(
    const float* __restrict__ hs, const float* __restrict__ W2,
    const float* __restrict__ b2, const float* __restrict__ u2,
    float* __restrict__ a2w) {
    int b  = blockIdx.x & 31;
    int tc = blockIdx.x >> 5;
    int a  = threadIdx.x;
    __shared__ __align__(16) float hl[16][kH];
    __shared__ float red[16][2];
    int t0 = tc * 16;
    for (int tt = 0; tt < 16; ++tt) {
        const float* hp = hs + ((size_t)(t0 + tt) * kB + b) * kH;
        hl[tt][a]       = hp[a];
        hl[tt][a + 128] = hp[a + 128];
    }
    __syncthreads();
    float dot[16];
#pragma unroll
    for (int tt = 0; tt < 16; ++tt) dot[tt] = 0.f;
    for (int k = 0; k < kH; k += 4) {
        float w0 = W2[(k + 0) * kA2 + a];
        float w1 = W2[(k + 1) * kA2 + a];
        float w2 = W2[(k + 2) * kA2 + a];
        float w3 = W2[(k + 3) * kA2 + a];
#pragma unroll
        for (int tt = 0; tt < 16; ++tt) {
            float4 h4 = *(const float4*)&hl[tt][k];
            dot[tt] = fmaf(h4.x, w0, dot[tt]);
            dot[tt] = fmaf(h4.y, w1, dot[tt]);
            dot[tt] = fmaf(h4.z, w2, dot[tt]);
            dot[tt] = fmaf(h4.w, w3, dot[tt]);
        }
    }
    float bb = b2[a], uu = u2[a];
    int wave = a >> 6, lane = a & 63;
#pragma unroll
    for (int tt = 0; tt < 16; ++tt) {
        float v = fast_tanh(dot[tt] + bb) * uu;
#pragma unroll
        for (int m = 32; m; m >>= 1) v += __shfl_xor(v, m, 64);
        if (lane == 0) red[tt][wave] = v;
    }
    __syncthreads();
    if (a < 16) {
        float s = red[a][0] + red[a][1];
        a2w[(t0 + a) * kB + b] = __expf(s);
    }
}

// ---------------- Kernel 3b: weighted time-pool + linear head ----------------
__global__ __launch_bounds__(256) void att2b_kernel(
    const float* __restrict__ hs, const float* __restrict__ a2w,
    const float* __restrict__ Wl, const float* __restrict__ bl,
    float* __restrict__ out) {
    int b = blockIdx.x;
    int k = threadIdx.x;
    float acc = 0.f, den = 0.f;
    for (int t = 0; t < kT; ++t) {
        float e = a2w[t * kB + b];
        float h = hs[((size_t)t * kB + b) * kH + k];
        acc = fmaf(h, e, acc);
        den += e;
    }
    float v = (acc / den) * Wl[k];
#pragma unroll
    for (int m = 32; m; m >>= 1) v += __shfl_xor(v, m, 64);
    __shared__ float red[4];
    int wave = k >> 6, lane = k & 63;
    if (lane == 0) red[wave] = v;
    __syncthreads();
    if (k == 0) out[b] = red[0] + red[1] + red[2] + red[3] + bl[0];
}

extern "C" void kernel_launch(void* const* d_in, const int* in_sizes, int n_in,
                              void* d_out, int out_size, void* d_ws, size_t ws_size,
                              hipStream_t stream) {
    const float* inputs = (const float*)d_in[0];
    const float* W1   = (const float*)d_in[1];
    const float* b1   = (const float*)d_in[2];
    const float* u1   = (const float*)d_in[3];
    const float* W_ih = (const float*)d_in[4];
    const float* W_hh = (const float*)d_in[5];
    const float* b_ih = (const float*)d_in[6];
    const float* b_hh = (const float*)d_in[7];
    const float* h0   = (const float*)d_in[8];
    const float* c0   = (const float*)d_in[9];
    const float* W2   = (const float*)d_in[10];
    const float* b2   = (const float*)d_in[11];
    const float* u2   = (const float*)d_in[12];
    const float* Wl   = (const float*)d_in[13];
    const float* bl   = (const float*)d_in[14];
    float* out = (float*)d_out;

    char* ws = (char*)d_ws;
    float*    seq = (float*)(ws);                    // 64 KB  (T*B fp32)
    float*    a2w = (float*)(ws + (64 << 10));       // 64 KB  (T*B fp32)
    _Float16* WQ  = (_Float16*)(ws + (128 << 10));   // 512 KB (4H*H fp16, packed)
    float*    hs  = (float*)(ws + (1 << 20));        // 16 MB  (T*B*H fp32)

    att1_kernel <<<kT * kB, 256, 0, stream>>>(inputs, W1, b1, u1, seq);
    wconv_kernel<<<512, 256, 0, stream>>>(W_hh, WQ);
    lstm_kernel <<<kB, 256, 0, stream>>>(seq, WQ, W_ih, b_ih, b_hh, h0, c0, hs);
    att2a_kernel<<<1024, 128, 0, stream>>>(hs, W2, b2, u2, a2w);
    att2b_kernel<<<kB, 256, 0, stream>>>(hs, a2w, Wl, bl, out);
}